// Round 1
// baseline (46.343 us; speedup 1.0000x reference)
//
#include <hip/hip_runtime.h>

// LIFSpike forward, T=4, tau=2, vth=1, vreset=0, decay_input=False, hard reset.
// x: (128,256,32,32) f32, viewed as (T=4, N=8388608) contiguous.
// per element i: v=0; for t: h = v*0.5 + x[t*N+i]; s = (h>=1); out = s; v = s?0:h.
// Pure streaming: 128 MiB read + 128 MiB write.

__global__ __launch_bounds__(256) void lif_spike_kernel(
    const float4* __restrict__ x, float4* __restrict__ out, int n4) {
    int idx = blockIdx.x * blockDim.x + threadIdx.x;
    int stride = gridDim.x * blockDim.x;
    for (int i = idx; i < n4; i += stride) {
        float4 v = make_float4(0.f, 0.f, 0.f, 0.f);
        #pragma unroll
        for (int t = 0; t < 4; ++t) {
            float4 xt = x[(size_t)t * n4 + i];
            float4 h;
            h.x = v.x * 0.5f + xt.x;
            h.y = v.y * 0.5f + xt.y;
            h.z = v.z * 0.5f + xt.z;
            h.w = v.w * 0.5f + xt.w;
            float4 s;
            s.x = (h.x >= 1.0f) ? 1.0f : 0.0f;
            s.y = (h.y >= 1.0f) ? 1.0f : 0.0f;
            s.z = (h.z >= 1.0f) ? 1.0f : 0.0f;
            s.w = (h.w >= 1.0f) ? 1.0f : 0.0f;
            out[(size_t)t * n4 + i] = s;
            // hard reset: v_next = h*(1-s) + vreset*s = (h>=1) ? 0 : h
            v.x = (h.x >= 1.0f) ? 0.0f : h.x;
            v.y = (h.y >= 1.0f) ? 0.0f : h.y;
            v.z = (h.z >= 1.0f) ? 0.0f : h.z;
            v.w = (h.w >= 1.0f) ? 0.0f : h.w;
        }
    }
}

extern "C" void kernel_launch(void* const* d_in, const int* in_sizes, int n_in,
                              void* d_out, int out_size, void* d_ws, size_t ws_size,
                              hipStream_t stream) {
    const float* x = (const float*)d_in[0];
    float* out = (float*)d_out;

    const int total = in_sizes[0];        // 33,554,432
    const int N = total / 4;              // per-timestep elements: 8,388,608
    const int n4 = N / 4;                 // float4 slots per timestep: 2,097,152

    const int block = 256;
    int grid = (n4 + block - 1) / block;
    if (grid > 2048) grid = 2048;

    lif_spike_kernel<<<grid, block, 0, stream>>>(
        (const float4*)x, (float4*)out, n4);
}

// Round 3
// 43.301 us; speedup vs baseline: 1.0702x; 1.0702x over previous
//
#include <hip/hip_runtime.h>

// LIFSpike forward, T=4, tau=2, vth=1, vreset=0, decay_input=False, hard reset.
// x: (128,256,32,32) f32, viewed as (T=4, N=8388608) contiguous.
// per element i: v=0; for t: h = v*0.5 + x[t*N+i]; s = (h>=1); out = s; v = s?0:h.
//
// Output (spikes) is write-once, never re-read -> nontemporal stores so the
// 134 MB of writes don't evict the 128 MiB input from the 256 MiB L3.
// Input stays L3-resident across graph replays -> HBM traffic ~= writes only.
//
// Note: __builtin_nontemporal_store requires a clang vector type, not HIP's
// float4 class -> use ext_vector_type(4).

typedef float f32x4 __attribute__((ext_vector_type(4)));

__global__ __launch_bounds__(256) void lif_spike_kernel(
    const f32x4* __restrict__ x, f32x4* __restrict__ out, int n4) {
    int i = blockIdx.x * blockDim.x + threadIdx.x;
    if (i >= n4) return;

    f32x4 v = (f32x4)(0.0f);
    #pragma unroll
    for (int t = 0; t < 4; ++t) {
        f32x4 xt = x[(size_t)t * n4 + i];
        f32x4 h = v * 0.5f + xt;
        f32x4 s;
        s.x = (h.x >= 1.0f) ? 1.0f : 0.0f;
        s.y = (h.y >= 1.0f) ? 1.0f : 0.0f;
        s.z = (h.z >= 1.0f) ? 1.0f : 0.0f;
        s.w = (h.w >= 1.0f) ? 1.0f : 0.0f;
        __builtin_nontemporal_store(s, &out[(size_t)t * n4 + i]);
        // hard reset: v_next = (h>=1) ? 0 : h
        v.x = (h.x >= 1.0f) ? 0.0f : h.x;
        v.y = (h.y >= 1.0f) ? 0.0f : h.y;
        v.z = (h.z >= 1.0f) ? 0.0f : h.z;
        v.w = (h.w >= 1.0f) ? 0.0f : h.w;
    }
}

extern "C" void kernel_launch(void* const* d_in, const int* in_sizes, int n_in,
                              void* d_out, int out_size, void* d_ws, size_t ws_size,
                              hipStream_t stream) {
    const float* x = (const float*)d_in[0];
    float* out = (float*)d_out;

    const int total = in_sizes[0];        // 33,554,432
    const int N = total / 4;              // per-timestep elements: 8,388,608
    const int n4 = N / 4;                 // float4 slots per timestep: 2,097,152

    const int block = 256;
    const int grid = (n4 + block - 1) / block;  // 8192 exact

    lif_spike_kernel<<<grid, block, 0, stream>>>(
        (const f32x4*)x, (f32x4*)out, n4);
}